// Round 2
// baseline (1521.214 us; speedup 1.0000x reference)
//
#include <hip/hip_runtime.h>
#include <hip/hip_bf16.h>
#include <stdint.h>

#define NN   100000
#define EE   3200000
#define HD   128

typedef short v8s __attribute__((ext_vector_type(8)));
typedef float v4f __attribute__((ext_vector_type(4)));

__device__ __forceinline__ unsigned short f2bf(float f){
  union { float f; unsigned int i; } v; v.f = f;
  unsigned int r = v.i + 0x7fffu + ((v.i >> 16) & 1u);
  return (unsigned short)(r >> 16);
}
__device__ __forceinline__ uint4 pack8(float4 lo, float4 hi){
  uint4 r;
  r.x = (unsigned)f2bf(lo.x) | ((unsigned)f2bf(lo.y) << 16);
  r.y = (unsigned)f2bf(lo.z) | ((unsigned)f2bf(lo.w) << 16);
  r.z = (unsigned)f2bf(hi.x) | ((unsigned)f2bf(hi.y) << 16);
  r.w = (unsigned)f2bf(hi.z) | ((unsigned)f2bf(hi.w) << 16);
  return r;
}

// ---------------- graph build ----------------
__global__ void k_zero(int* p, int n){
  int i = blockIdx.x*blockDim.x + threadIdx.x; if (i < n) p[i] = 0;
}
__global__ void k_hist(const int* __restrict__ dst, int* __restrict__ cnt, int e){
  int i = blockIdx.x*blockDim.x + threadIdx.x;
  if (i < e) atomicAdd(&cnt[dst[i]], 1);
}
__global__ __launch_bounds__(1024)
void k_scan1(const int* __restrict__ cnt, int* __restrict__ offs, int* __restrict__ blksum, int n){
  __shared__ int lds[1024];
  int t = threadIdx.x; int i = blockIdx.x*1024 + t;
  int v = (i < n) ? cnt[i] : 0;
  lds[t] = v; __syncthreads();
  for (int s = 1; s < 1024; s <<= 1){
    int add = (t >= s) ? lds[t-s] : 0;
    __syncthreads();
    lds[t] += add;
    __syncthreads();
  }
  if (i < n) offs[i] = lds[t] - v;           // exclusive
  if (t == 1023) blksum[blockIdx.x] = lds[1023];
}
__global__ void k_scan2(int* blksum, int nb){
  if (threadIdx.x == 0 && blockIdx.x == 0){
    int run = 0;
    for (int b = 0; b < nb; b++){ int t = blksum[b]; blksum[b] = run; run += t; }
  }
}
__global__ __launch_bounds__(1024)
void k_scan3(int* __restrict__ offs, const int* __restrict__ blksum, int* __restrict__ fill, int n){
  int i = blockIdx.x*1024 + threadIdx.x;
  if (i < n){ int o = offs[i] + blksum[blockIdx.x]; offs[i] = o; fill[i] = o; }
}
__global__ void k_scatter(const int* __restrict__ src, const int* __restrict__ dst,
                          int* __restrict__ fill, int* __restrict__ ssrc, int e){
  int i = blockIdx.x*blockDim.x + threadIdx.x;
  if (i < e){ int p = atomicAdd(&fill[dst[i]], 1); ssrc[p] = src[i]; }
}

// -------- bf16-MFMA GEMM with fp32 inputs: C_bf16[M,128] = relu?(A@B^T + bias) --------
// A segments may be fp32 (inputs) or bf16 (our workspace); B (weights) always fp32.
// fp32 data is rounded to bf16 during LDS staging.
__device__ __forceinline__ void gemm_issue(int t, int T0, int M, int gm, int r0, int c8,
    const void* __restrict__ A0, int lda0, int a0f32,
    const void* __restrict__ A1, int lda1, int a1f32,
    const float* __restrict__ B0, int ldb0,
    const float* __restrict__ B1, int ldb1,
    uint4* as, uint4* bs)
{
  const void* Ag; const float* Bg; int la, lb, ko, af32;
  if (t < T0){ Ag = A0; la = lda0; af32 = a0f32; Bg = B0; lb = ldb0; ko = t*64; }
  else       { Ag = A1; la = lda1; af32 = a1f32; Bg = B1; lb = ldb1; ko = (t-T0)*64; }
#pragma unroll
  for (int p = 0; p < 4; p++){
    int row  = r0 + p*32;
    int grow = gm + row;
    if (grow < M){
      if (af32){
        const float* ap = (const float*)Ag + (size_t)grow*la + ko + c8;
        as[p] = pack8(*(const float4*)ap, *(const float4*)(ap + 4));
      } else {
        as[p] = *(const uint4*)((const unsigned short*)Ag + (size_t)grow*la + ko + c8);
      }
    } else {
      as[p] = make_uint4(0u,0u,0u,0u);
    }
    const float* bp = Bg + (size_t)row*lb + ko + c8;
    bs[p] = pack8(*(const float4*)bp, *(const float4*)(bp + 4));
  }
}

__global__ __launch_bounds__(256)
void k_gemm(int M,
            const void* __restrict__ A0, int lda0, int K0, int a0f32,
            const void* __restrict__ A1, int lda1, int K1, int a1f32,
            const float* __restrict__ B0, int ldb0,
            const float* __restrict__ B1, int ldb1,
            const float* __restrict__ bias, int do_relu,
            unsigned short* __restrict__ C, int ldc)
{
  __shared__ unsigned short Abuf[128*72];   // BK=64 bf16, pad 8
  __shared__ unsigned short Bbuf[128*72];
  const int tid = threadIdx.x;
  const int gm  = blockIdx.x * 128;
  const int T0  = K0 >> 6;
  const int T   = (K0 + K1) >> 6;

  const int r0 = tid >> 3;          // 0..31
  const int c8 = (tid & 7) * 8;     // 0..56

  const int lane = tid & 63;
  const int w  = tid >> 6;
  const int wm = w >> 1, wn = w & 1;
  const int l15 = lane & 15, q = lane >> 4;

  v4f acc[4][4];
#pragma unroll
  for (int mi = 0; mi < 4; mi++)
#pragma unroll
    for (int ni = 0; ni < 4; ni++){ v4f z = {0.f,0.f,0.f,0.f}; acc[mi][ni] = z; }

  uint4 aS[4], bS[4];
  gemm_issue(0, T0, M, gm, r0, c8, A0, lda0, a0f32, A1, lda1, a1f32,
             B0, ldb0, B1, ldb1, aS, bS);

  for (int t = 0; t < T; ++t){
#pragma unroll
    for (int p = 0; p < 4; p++){
      int row = r0 + p*32;
      *(uint4*)(Abuf + row*72 + c8) = aS[p];
      *(uint4*)(Bbuf + row*72 + c8) = bS[p];
    }
    __syncthreads();
    if (t + 1 < T)
      gemm_issue(t+1, T0, M, gm, r0, c8, A0, lda0, a0f32, A1, lda1, a1f32,
                 B0, ldb0, B1, ldb1, aS, bS);
#pragma unroll
    for (int kk = 0; kk < 64; kk += 32){
      v8s af[4], bf[4];
#pragma unroll
      for (int mi = 0; mi < 4; mi++)
        af[mi] = *(const v8s*)(Abuf + (wm*64 + mi*16 + l15)*72 + kk + q*8);
#pragma unroll
      for (int ni = 0; ni < 4; ni++)
        bf[ni] = *(const v8s*)(Bbuf + (wn*64 + ni*16 + l15)*72 + kk + q*8);
#pragma unroll
      for (int mi = 0; mi < 4; mi++)
#pragma unroll
        for (int ni = 0; ni < 4; ni++)
          acc[mi][ni] = __builtin_amdgcn_mfma_f32_16x16x32_bf16(af[mi], bf[ni], acc[mi][ni], 0, 0, 0);
    }
    __syncthreads();
  }

  // epilogue: D col = lane&15, row = (lane>>4)*4 + reg (m89-verified mapping)
#pragma unroll
  for (int ni = 0; ni < 4; ni++){
    int n = wn*64 + ni*16 + l15;
    float bv = bias ? bias[n] : 0.0f;
#pragma unroll
    for (int mi = 0; mi < 4; mi++){
#pragma unroll
      for (int r = 0; r < 4; r++){
        int row = gm + wm*64 + mi*16 + q*4 + r;
        if (row < M){
          float v = acc[mi][ni][r] + bv;
          if (do_relu) v = v > 0.f ? v : 0.f;
          C[(size_t)row*ldc + n] = f2bf(v);
        }
      }
    }
  }
}

// ---------------- layer-1 aggregate + finish + fused C=4 projections ----------------
// one wave per node: x2 = relu(mean(y1[nbrs]) + z1); y2 = x2@Wl2^T; r2 = x2@Wr2^T + bl2
__global__ __launch_bounds__(256)
void k_agg1(const int* __restrict__ offs, const int* __restrict__ cnt,
            const int* __restrict__ ssrc,
            const unsigned short* __restrict__ y1,
            const unsigned short* __restrict__ z1,
            const float* __restrict__ Wl2,
            const float* __restrict__ Wr2,
            const float* __restrict__ bl2,
            float* __restrict__ y2, float* __restrict__ r2, int n)
{
  int wid  = (blockIdx.x * blockDim.x + threadIdx.x) >> 6;
  int lane = threadIdx.x & 63;
  if (wid >= n) return;
  int start = offs[wid];
  int deg   = cnt[wid];
  const unsigned int* y1u = (const unsigned int*)y1;  // 2 bf16 per uint; lane covers feats 2l, 2l+1
  float a0 = 0.f, a1 = 0.f;
  for (int base = 0; base < deg; base += 64){
    int idx = base + lane;
    int sl  = (idx < deg) ? ssrc[start + idx] : 0;
    int m   = deg - base; if (m > 64) m = 64;
    for (int t = 0; t < m; ++t){
      int s = __shfl(sl, t, 64);
      unsigned int u = y1u[(size_t)s*64 + lane];
      union {unsigned int i; float f;} lo, hi;
      lo.i = u << 16; hi.i = u & 0xffff0000u;
      a0 += lo.f; a1 += hi.f;
    }
  }
  float scale = 1.0f / (float)(deg > 0 ? deg : 1);
  unsigned int zu = ((const unsigned int*)z1)[(size_t)wid*64 + lane];
  union {unsigned int i; float f;} zl, zh;
  zl.i = zu << 16; zh.i = zu & 0xffff0000u;
  float x0 = a0*scale + zl.f; x0 = x0 > 0.f ? x0 : 0.f;
  float x1 = a1*scale + zh.f; x1 = x1 > 0.f ? x1 : 0.f;

  float pl[4], pr[4];
#pragma unroll
  for (int c = 0; c < 4; c++){
    float2 wl = ((const float2*)Wl2)[c*64 + lane];   // feats 2l, 2l+1 of row c
    float2 wr = ((const float2*)Wr2)[c*64 + lane];
    pl[c] = x0*wl.x + x1*wl.y;
    pr[c] = x0*wr.x + x1*wr.y;
  }
#pragma unroll
  for (int off = 32; off > 0; off >>= 1){
#pragma unroll
    for (int c = 0; c < 4; c++){
      pl[c] += __shfl_xor(pl[c], off, 64);
      pr[c] += __shfl_xor(pr[c], off, 64);
    }
  }
  if (lane < 4){
    y2[(size_t)wid*4 + lane] = pl[lane];
    r2[(size_t)wid*4 + lane] = pr[lane] + bl2[lane];
  }
}

// ---------------- layer-2 aggregate + fp32 output ----------------
__global__ void k_agg2(const int* __restrict__ offs, const int* __restrict__ cnt,
                       const int* __restrict__ ssrc,
                       const float* __restrict__ y2, const float* __restrict__ r2,
                       float* __restrict__ out, int n)
{
  int i = blockIdx.x * blockDim.x + threadIdx.x;
  if (i >= n) return;
  int start = offs[i], deg = cnt[i];
  float a0 = 0.f, a1 = 0.f, a2 = 0.f, a3 = 0.f;
  for (int e = 0; e < deg; e++){
    int s = ssrc[start + e];
    float4 v = *(const float4*)(y2 + (size_t)s*4);
    a0 += v.x; a1 += v.y; a2 += v.z; a3 += v.w;
  }
  float sc = 1.0f / (float)(deg > 0 ? deg : 1);
  float4 r = *(const float4*)(r2 + (size_t)i*4);
  float4 o;
  o.x = a0*sc + r.x; o.y = a1*sc + r.y; o.z = a2*sc + r.z; o.w = a3*sc + r.w;
  *(float4*)(out + (size_t)i*4) = o;
}

extern "C" void kernel_launch(void* const* d_in, const int* in_sizes, int n_in,
                              void* d_out, int out_size, void* d_ws, size_t ws_size,
                              hipStream_t stream)
{
  (void)in_sizes; (void)n_in; (void)out_size; (void)ws_size;
  const float* clinical = (const float*)d_in[0];
  const float* mel      = (const float*)d_in[1];
  const int*   ei       = (const int*)d_in[2];
  const float* Wm  = (const float*)d_in[3];
  const float* bm  = (const float*)d_in[4];
  const float* Wc  = (const float*)d_in[5];
  const float* bc  = (const float*)d_in[6];
  const float* Wl1 = (const float*)d_in[7];
  const float* bl1 = (const float*)d_in[8];
  const float* Wr1 = (const float*)d_in[9];
  const float* Wl2 = (const float*)d_in[10];
  const float* bl2 = (const float*)d_in[11];
  const float* Wr2 = (const float*)d_in[12];
  const int* src = ei;
  const int* dst = ei + EE;

  char* w = (char*)d_ws;
  auto alloc = [&](size_t sz){ void* p = (void*)w; w += (sz + 255) & ~(size_t)255; return p; };
  unsigned short* mel_h = (unsigned short*)alloc((size_t)NN*HD*2);  // reused as y1 after GEMM2
  unsigned short* x     = (unsigned short*)alloc((size_t)NN*HD*2);
  unsigned short* z1    = (unsigned short*)alloc((size_t)NN*HD*2);
  int*   ssrc   = (int*)alloc((size_t)EE*4);
  int*   cnt    = (int*)alloc((size_t)NN*4);
  int*   offs   = (int*)alloc((size_t)NN*4);
  int*   fill   = (int*)alloc((size_t)NN*4);
  int*   blksum = (int*)alloc(4096);
  float* y2     = (float*)alloc((size_t)NN*4*4);
  float* r2     = (float*)alloc((size_t)NN*4*4);

  // --- CSR build ---
  k_zero<<<(NN+255)/256, 256, 0, stream>>>(cnt, NN);
  k_hist<<<(EE+255)/256, 256, 0, stream>>>(dst, cnt, EE);
  int nblk = (NN + 1023) / 1024;  // 98
  k_scan1<<<nblk, 1024, 0, stream>>>(cnt, offs, blksum, NN);
  k_scan2<<<1, 64, 0, stream>>>(blksum, nblk);
  k_scan3<<<nblk, 1024, 0, stream>>>(offs, blksum, fill, NN);
  k_scatter<<<(EE+255)/256, 256, 0, stream>>>(src, dst, fill, ssrc, EE);

  int gmb = (NN + 127) / 128;     // 782 row tiles
  // mel_h = relu(mel @ Wm^T + bm)          (A fp32, B fp32)
  k_gemm<<<gmb, 256, 0, stream>>>(NN, mel, 1280, 1280, 1, nullptr, 0, 0, 0,
                                  Wm, 1280, nullptr, 0, bm, 1, mel_h, HD);
  // x = relu([clinical | mel_h] @ Wc^T + bc)   (seg0 fp32 K=64, seg1 bf16 K=128)
  k_gemm<<<gmb, 256, 0, stream>>>(NN, clinical, 64, 64, 1, mel_h, HD, HD, 0,
                                  Wc, 192, Wc + 64, 192, bc, 1, x, HD);
  // y1 = x @ Wl1^T   (into mel_h buffer — mel_h dead after GEMM2)
  unsigned short* y1 = mel_h;
  k_gemm<<<gmb, 256, 0, stream>>>(NN, x, HD, HD, 0, nullptr, 0, 0, 0,
                                  Wl1, HD, nullptr, 0, nullptr, 0, y1, HD);
  // z1 = x @ Wr1^T + bl1
  k_gemm<<<gmb, 256, 0, stream>>>(NN, x, HD, HD, 0, nullptr, 0, 0, 0,
                                  Wr1, HD, nullptr, 0, bl1, 0, z1, HD);

  // layer-1 aggregate + relu + fused layer-2 projections
  k_agg1<<<(NN+3)/4, 256, 0, stream>>>(offs, cnt, ssrc, y1, z1, Wl2, Wr2, bl2, y2, r2, NN);
  // layer-2 aggregate + fp32 output
  k_agg2<<<(NN+255)/256, 256, 0, stream>>>(offs, cnt, ssrc, y2, r2, (float*)d_out, NN);
}